// Round 6
// baseline (98.582 us; speedup 1.0000x reference)
//
#include <hip/hip_runtime.h>
#include <hip/hip_bf16.h>
#include <math.h>

#define SEQ 4096
#define HD  64
#define NBATCH 4

#define EM1  1.71828182845904523536f
#define INVD5 (1.0f/(4096.f + 5.f*EM1))
#define INVD4 (1.0f/(4096.f + 4.f*EM1))
#define INVD3 (1.0f/(4096.f + 3.f*EM1))

typedef __attribute__((ext_vector_type(8))) short short8;
typedef __attribute__((ext_vector_type(4))) float f32x4;

__device__ __forceinline__ f32x4 mfma16(short8 a, short8 b, f32x4 c) {
    return __builtin_amdgcn_mfma_f32_16x16x32_bf16(a, b, c, 0, 0, 0);
}

__device__ __forceinline__ short bfs(float x) {
    __hip_bfloat16 h = __float2bfloat16(x);
    return *(short*)&h;
}

__device__ __forceinline__ short8 pack8(float4 a, float4 b) {
    short8 r;
    r[0] = bfs(a.x); r[1] = bfs(a.y); r[2] = bfs(a.z); r[3] = bfs(a.w);
    r[4] = bfs(b.x); r[5] = bfs(b.y); r[6] = bfs(b.z); r[7] = bfs(b.w);
    return r;
}

__device__ __forceinline__ float blo(unsigned v) { return __uint_as_float(v << 16); }
__device__ __forceinline__ float bhi(unsigned v) { return __uint_as_float(v & 0xffff0000u); }

// ---------------------------------------------------------------------------
// Kernel 1: projections via MFMA, m-split for occupancy.
// grid (1024, 3): x = 16-row block, y = which matrix (q/k/v).  64 threads.
//   qsb bf16 [B,S,H] = q/8 ;  ktb/vtb bf16 [B,H,S] transposed
//   kpart/vpart fp32 [1024][64] per-block column sums (incl. 16*bias)
// ---------------------------------------------------------------------------
__global__ __launch_bounds__(64) void proj_kernel(
    const float* __restrict__ feat,
    const float* __restrict__ Wq, const float* __restrict__ bq,
    const float* __restrict__ Wk, const float* __restrict__ bk,
    const float* __restrict__ Wv, const float* __restrict__ bv,
    __hip_bfloat16* __restrict__ qsb, __hip_bfloat16* __restrict__ ktb,
    __hip_bfloat16* __restrict__ vtb,
    float* __restrict__ kpart, float* __restrict__ vpart)
{
    __shared__ __hip_bfloat16 tscr[16 * 66];

    const int tid  = threadIdx.x;              // one wave
    const int quad = tid >> 4, ln = tid & 15;
    const int mi = blockIdx.y;
    const int R0 = blockIdx.x * 16;            // [0, B*S)
    const int b  = R0 >> 12;
    const int t0 = R0 & (SEQ - 1);

    const float* W    = (mi == 0) ? Wq : (mi == 1) ? Wk : Wv;
    const float* bias = (mi == 0) ? bq : (mi == 1) ? bk : bv;

    short8 af0, af1;
    {
        const float* fp = feat + (size_t)(R0 + ln) * HD + quad * 8;
        af0 = pack8(*(const float4*)(fp),      *(const float4*)(fp + 4));
        af1 = pack8(*(const float4*)(fp + 32), *(const float4*)(fp + 36));
    }

    float colsum[4];
    #pragma unroll
    for (int ct = 0; ct < 4; ++ct) {
        const int col = ct * 16 + ln;
        const float* wp = W + (size_t)col * HD + quad * 8;
        short8 b0 = pack8(*(const float4*)(wp),      *(const float4*)(wp + 4));
        short8 b1 = pack8(*(const float4*)(wp + 32), *(const float4*)(wp + 36));
        f32x4 c = {};
        c = mfma16(af0, b0, c);
        c = mfma16(af1, b1, c);
        const float bl = bias[col];

        if (mi == 0) {
            #pragma unroll
            for (int r = 0; r < 4; ++r)
                qsb[(size_t)(R0 + quad * 4 + r) * HD + col] =
                    __float2bfloat16((c[r] + bl) * 0.125f);
        } else {
            float tot = c[0] + c[1] + c[2] + c[3];
            tot += __shfl_xor(tot, 16);
            tot += __shfl_xor(tot, 32);
            colsum[ct] = tot;
            #pragma unroll
            for (int r = 0; r < 4; ++r)
                tscr[(quad * 4 + r) * 66 + col] = __float2bfloat16(c[r] + bl);
        }
    }

    if (mi != 0) {
        __syncthreads();
        float* part = (mi == 1) ? kpart : vpart;
        if (quad == 0) {
            #pragma unroll
            for (int ct = 0; ct < 4; ++ct) {
                const int col = ct * 16 + ln;
                part[(size_t)blockIdx.x * 64 + col] = colsum[ct] + 16.f * bias[col];
            }
        }
        __hip_bfloat16* dst = (mi == 1) ? ktb : vtb;
        #pragma unroll
        for (int i = 0; i < 2; ++i) {
            const int tsk = i * 64 + tid;          // 128 tasks: 64 h x 2 chunks
            const int hh = tsk >> 1, c8 = tsk & 1;
            short8 vv;
            #pragma unroll
            for (int j = 0; j < 8; ++j)
                vv[j] = *(const short*)&tscr[(c8 * 8 + j) * 66 + hh];
            *(short8*)(dst + ((size_t)(b * HD + hh)) * SEQ + t0 + c8 * 8) = vv;
        }
    }
}

// ---------------------------------------------------------------------------
// Kernel 2: per-chunk (32 t) partial of M[h1][h2] = sum_t mk[t][h1]*v[t][h2].
// grid (128, B), 256 thr (4 waves).  K=32 -> one MFMA k-step per tile.
// ---------------------------------------------------------------------------
__global__ __launch_bounds__(256) void mkernel(
    const __hip_bfloat16* __restrict__ ktb, const __hip_bfloat16* __restrict__ vtb,
    const float* __restrict__ kpart, float* __restrict__ Mpart)
{
    __shared__ float kts[64 * 38];              // [h][t0-2 .. t0+34), stride 38
    __shared__ __hip_bfloat16 mkt[64 * 40];     // mk^T [h][32t], stride 40
    __shared__ __hip_bfloat16 vts[64 * 40];     // v^T  [h][32t], stride 40
    __shared__ float ktl[64];
    __shared__ float red[4][64];

    const int tid = threadIdx.x;
    const int b = blockIdx.y, chunk = blockIdx.x;
    const int t0 = chunk * 32;
    const int h = tid & 63, g = tid >> 6;

    // ktot: reduce 256 per-batch kpart entries
    {
        float kp = 0.f;
        for (int j = 0; j < 64; ++j)
            kp += kpart[(size_t)(b * 256 + g * 64 + j) * 64 + h];
        red[g][h] = kp;
    }

    // stage k window [t0-2, t0+34) as fp32, zero-padded at sequence edges
    for (int i = tid; i < 64 * 18; i += 256) {
        const int r = i / 18, c = i - r * 18;
        const int gt = t0 - 2 + c * 2;
        unsigned val = 0;
        if (gt >= 0 && gt <= SEQ - 2)
            val = *(const unsigned*)(ktb + (size_t)(b * 64 + r) * SEQ + gt);
        kts[r * 38 + c * 2]     = blo(val);
        kts[r * 38 + c * 2 + 1] = bhi(val);
    }
    // stage v^T tile: 256 tasks of 16B
    {
        const int r = tid >> 2, c = tid & 3;
        *(uint4*)&vts[r * 40 + c * 8] =
            ((const uint4*)(vtb + (size_t)(b * 64 + r) * SEQ + t0))[c];
    }
    __syncthreads();
    if (tid < 64) ktl[tid] = red[0][tid] + red[1][tid] + red[2][tid] + red[3][tid];
    __syncthreads();

    // mk^T: wave g handles t-strip [t0+g*8, +8), one h per lane
    {
        const int tb = g * 8;
        float w[12];
        #pragma unroll
        for (int j = 0; j < 12; ++j) w[j] = kts[h * 38 + tb + j];
        const float ktv = ktl[h];
        short8 o;
        #pragma unroll
        for (int i = 0; i < 8; ++i) {
            const int t = t0 + tb + i;
            float invD = INVD5;
            if (t < 2)            invD = (t == 0) ? INVD3 : INVD4;
            else if (t > SEQ - 3) invD = (t == SEQ - 1) ? INVD3 : INVD4;
            const float loc = w[i] + w[i+1] + w[i+2] + w[i+3] + w[i+4];
            o[i] = bfs((EM1 * loc + ktv) * invD);
        }
        *(short8*)&mkt[h * 40 + tb] = o;
    }
    __syncthreads();

    // MFMA: wave owns h1-strip wave*16; A = mk^T rows, B = v^T rows, K=32
    const int wave = g, lane = tid & 63, quad = lane >> 4, ln = lane & 15;
    short8 a = *(const short8*)&mkt[(wave * 16 + ln) * 40 + quad * 8];
    f32x4 acc[4] = {};
    #pragma unroll
    for (int ct = 0; ct < 4; ++ct) {
        short8 bb = *(const short8*)&vts[(ct * 16 + ln) * 40 + quad * 8];
        acc[ct] = mfma16(a, bb, acc[ct]);
    }
    const size_t mb = (size_t)(b * 128 + chunk) * 4096;
    #pragma unroll
    for (int ct = 0; ct < 4; ++ct)
        #pragma unroll
        for (int r = 0; r < 4; ++r)
            Mpart[mb + (size_t)(wave * 16 + quad * 4 + r) * 64 + ct * 16 + ln] = acc[ct][r];
}

// ---------------------------------------------------------------------------
// Kernel 3: reduce Mpart -> MT bf16 [B][80][64] (row 64 = mktot closed form,
// rows 65..79 zero) ; Vtot fp32 [B][64].  grid (64, B), 256 thr.
// ---------------------------------------------------------------------------
__global__ __launch_bounds__(256) void mreduce_kernel(
    const float* __restrict__ Mpart, const float* __restrict__ kpart,
    const float* __restrict__ vpart, const __hip_bfloat16* __restrict__ ktb,
    __hip_bfloat16* __restrict__ MT, float* __restrict__ Vtot)
{
    __shared__ float red[4][64];
    const int b = blockIdx.y, h1 = blockIdx.x;
    const int tid = threadIdx.x;
    const int g = tid >> 6, h2 = tid & 63;

    float s = 0.f;
    for (int c = 0; c < 32; ++c)
        s += Mpart[(size_t)(b * 128 + g * 32 + c) * 4096 + h1 * 64 + h2];
    red[g][h2] = s;
    __syncthreads();
    if (tid < 64)
        MT[(size_t)b * 5120 + tid * 64 + h1] =
            __float2bfloat16(red[0][tid] + red[1][tid] + red[2][tid] + red[3][tid]);

    if (h1 == 0 && tid < 64) {
        const int hh = tid;
        float kt = 0.f;
        for (int j = 0; j < 256; ++j)
            kt += kpart[(size_t)(b * 256 + j) * 64 + hh];
        const __hip_bfloat16* kr = ktb + (size_t)(b * 64 + hh) * SEQ;
        const float e0 = __bfloat162float(kr[0]), e1 = __bfloat162float(kr[1]);
        const float e2 = __bfloat162float(kr[2]), e3 = __bfloat162float(kr[3]);
        const float f0 = __bfloat162float(kr[SEQ-4]), f1 = __bfloat162float(kr[SEQ-3]);
        const float f2 = __bfloat162float(kr[SEQ-2]), f3 = __bfloat162float(kr[SEQ-1]);
        const float Sint = 5.f*kt - 4.f*e0 - 3.f*e1 - 2.f*e2 - e3
                         - f0 - 2.f*f1 - 3.f*f2 - 4.f*f3;
        const float SlocD = Sint * INVD5
                          + (e0+e1+e2 + f1+f2+f3) * INVD3
                          + (e0+e1+e2+e3 + f0+f1+f2+f3) * INVD4;
        const float mktot = kt * (4092.f*INVD5 + 2.f*INVD4 + 2.f*INVD3) + EM1 * SlocD;
        MT[(size_t)b * 5120 + 64 * 64 + hh] = __float2bfloat16(mktot);
    }
    if (h1 == 1 && tid < 64) {
        float s2 = 0.f;
        for (int j = 0; j < 256; ++j)
            s2 += vpart[(size_t)(b * 256 + j) * 64 + tid];
        Vtot[b * 64 + tid] = s2;
    }
    if (h1 == 2) {
        for (int i = tid; i < 15 * 64; i += 256)
            MT[(size_t)b * 5120 + 65 * 64 + i] = __float2bfloat16(0.f);
    }
}

// ---------------------------------------------------------------------------
// Kernel 4: out[row] = (Vtot + qs·M) / (4096 + qs·mktot) via MFMA.
// grid 1024, 64 thr (one wave, 16 rows).  MT is 40 KB, L2-resident.
// ---------------------------------------------------------------------------
__global__ __launch_bounds__(64) void out_kernel(
    const __hip_bfloat16* __restrict__ qsb, const __hip_bfloat16* __restrict__ MT,
    const float* __restrict__ Vtot, float* __restrict__ out)
{
    const int tid = threadIdx.x;
    const int quad = tid >> 4, ln = tid & 15;
    const int R0 = blockIdx.x * 16;
    const int b = R0 >> 12;

    short8 qa0, qa1;
    {
        const __hip_bfloat16* qp = qsb + (size_t)(R0 + ln) * HD + quad * 8;
        qa0 = *(const short8*)qp;
        qa1 = *(const short8*)(qp + 32);
    }

    const __hip_bfloat16* mtb = MT + (size_t)b * 5120;
    f32x4 acc[5] = {};
    #pragma unroll
    for (int ct = 0; ct < 5; ++ct) {
        short8 b0 = *(const short8*)(mtb + (ct * 16 + ln) * 64 + quad * 8);
        short8 b1 = *(const short8*)(mtb + (ct * 16 + ln) * 64 + 32 + quad * 8);
        acc[ct] = mfma16(qa0, b0, acc[ct]);
        acc[ct] = mfma16(qa1, b1, acc[ct]);
    }

    float vt[4];
    #pragma unroll
    for (int ct = 0; ct < 4; ++ct) vt[ct] = Vtot[b * 64 + ct * 16 + ln];

    float inv[4];
    #pragma unroll
    for (int r = 0; r < 4; ++r) {
        const float den = __shfl(acc[4][r], tid & 48);   // col 0 of ct=4 tile
        inv[r] = 1.f / (4096.f + den);
    }
    #pragma unroll
    for (int ct = 0; ct < 4; ++ct)
        #pragma unroll
        for (int r = 0; r < 4; ++r)
            out[(size_t)(R0 + quad * 4 + r) * HD + ct * 16 + ln] =
                (vt[ct] + acc[ct][r]) * inv[r];
}

// ---------------------------------------------------------------------------
extern "C" void kernel_launch(void* const* d_in, const int* in_sizes, int n_in,
                              void* d_out, int out_size, void* d_ws, size_t ws_size,
                              hipStream_t stream)
{
    const float* feat = (const float*)d_in[0];
    const float* Wq = (const float*)d_in[1];
    const float* bq = (const float*)d_in[2];
    const float* Wk = (const float*)d_in[3];
    const float* bk = (const float*)d_in[4];
    const float* Wv = (const float*)d_in[5];
    const float* bv = (const float*)d_in[6];
    float* out = (float*)d_out;

    char* ws = (char*)d_ws;
    __hip_bfloat16* qsb   = (__hip_bfloat16*)(ws + 0);            // 2 MB
    __hip_bfloat16* ktb   = (__hip_bfloat16*)(ws + (2u << 20));   // 2 MB
    __hip_bfloat16* vtb   = (__hip_bfloat16*)(ws + (4u << 20));   // 2 MB
    float*          kpart = (float*)(ws + (6u << 20));            // 256 KB
    float*          vpart = (float*)(ws + (6u << 20) + 262144);   // 256 KB
    float*          Mpart = (float*)(ws + (6u << 20) + 524288);   // 8 MB
    __hip_bfloat16* MT    = (__hip_bfloat16*)(ws + (14u << 20) + 524288);  // 40 KB
    float*          Vtot  = (float*)(ws + (14u << 20) + 524288 + 40960);   // 1 KB

    proj_kernel<<<dim3(1024, 3), dim3(64), 0, stream>>>(
        feat, Wq, bq, Wk, bk, Wv, bv, qsb, ktb, vtb, kpart, vpart);
    mkernel<<<dim3(128, NBATCH), dim3(256), 0, stream>>>(ktb, vtb, kpart, Mpart);
    mreduce_kernel<<<dim3(64, NBATCH), dim3(256), 0, stream>>>(
        Mpart, kpart, vpart, ktb, MT, Vtot);
    out_kernel<<<dim3(1024), dim3(64), 0, stream>>>(qsb, MT, Vtot, out);
}

// Round 8
// 89.612 us; speedup vs baseline: 1.1001x; 1.1001x over previous
//
#include <hip/hip_runtime.h>
#include <hip/hip_bf16.h>
#include <math.h>

#define SEQ 4096
#define HD  64
#define NBATCH 4

#define EM1   1.71828182845904523536f
#define INVD5 (1.0f/(4096.f + 5.f*EM1))
#define INVD4 (1.0f/(4096.f + 4.f*EM1))
#define INVD3 (1.0f/(4096.f + 3.f*EM1))

typedef __attribute__((ext_vector_type(8))) short short8;
typedef __attribute__((ext_vector_type(4))) float f32x4;

__device__ __forceinline__ f32x4 mfma16(short8 a, short8 b, f32x4 c) {
    return __builtin_amdgcn_mfma_f32_16x16x32_bf16(a, b, c, 0, 0, 0);
}

__device__ __forceinline__ short bfs(float x) {
    __hip_bfloat16 h = __float2bfloat16(x);
    return *(short*)&h;
}

__device__ __forceinline__ short8 pack8(float4 a, float4 b) {
    short8 r;
    r[0] = bfs(a.x); r[1] = bfs(a.y); r[2] = bfs(a.z); r[3] = bfs(a.w);
    r[4] = bfs(b.x); r[5] = bfs(b.y); r[6] = bfs(b.z); r[7] = bfs(b.w);
    return r;
}

__device__ __forceinline__ float blo(unsigned v) { return __uint_as_float(v << 16); }
__device__ __forceinline__ float bhi(unsigned v) { return __uint_as_float(v & 0xffff0000u); }
__device__ __forceinline__ float b2f(__hip_bfloat16 h) { return __bfloat162float(h); }

// ---------------------------------------------------------------------------
// Kernel 1: projections via MFMA.  512 blocks x 128 thr (2 waves, 32 rows).
// feat loaded ONCE for q,k,v.
//   qsb bf16 [B,S,H] = q/8 ; ktb/vtb bf16 [B,H,S] ; kpart/vpart fp32 [512][64]
// ---------------------------------------------------------------------------
__global__ __launch_bounds__(128) void proj_kernel(
    const float* __restrict__ feat,
    const float* __restrict__ Wq, const float* __restrict__ bq,
    const float* __restrict__ Wk, const float* __restrict__ bk,
    const float* __restrict__ Wv, const float* __restrict__ bv,
    __hip_bfloat16* __restrict__ qsb, __hip_bfloat16* __restrict__ ktb,
    __hip_bfloat16* __restrict__ vtb,
    float* __restrict__ kpart, float* __restrict__ vpart)
{
    __shared__ __hip_bfloat16 tscr[32 * 66];
    __shared__ float kred[2][64];

    const int tid  = threadIdx.x;
    const int wave = tid >> 6, lane = tid & 63;
    const int quad = lane >> 4, ln = lane & 15;
    const int R0 = blockIdx.x * 32;            // [0, B*S)
    const int b  = R0 >> 12;
    const int t0 = R0 & (SEQ - 1);

    short8 af0, af1;
    {
        const float* fp = feat + (size_t)(R0 + wave * 16 + ln) * HD + quad * 8;
        af0 = pack8(*(const float4*)(fp),      *(const float4*)(fp + 4));
        af1 = pack8(*(const float4*)(fp + 32), *(const float4*)(fp + 36));
    }

    const float* Ws[3] = {Wq, Wk, Wv};
    const float* Bs[3] = {bq, bk, bv};

    #pragma unroll
    for (int m = 0; m < 3; ++m) {
        const float* W = Ws[m];
        const float* bias = Bs[m];
        #pragma unroll
        for (int ct = 0; ct < 4; ++ct) {
            const int col = ct * 16 + ln;
            const float* wp = W + (size_t)col * HD + quad * 8;
            short8 b0 = pack8(*(const float4*)(wp),      *(const float4*)(wp + 4));
            short8 b1 = pack8(*(const float4*)(wp + 32), *(const float4*)(wp + 36));
            f32x4 c = {};
            c = mfma16(af0, b0, c);
            c = mfma16(af1, b1, c);
            const float bl = bias[col];

            if (m == 0) {
                #pragma unroll
                for (int r = 0; r < 4; ++r)
                    qsb[(size_t)(R0 + wave * 16 + quad * 4 + r) * HD + col] =
                        __float2bfloat16((c[r] + bl) * 0.125f);
            } else {
                float tot = c[0] + c[1] + c[2] + c[3];
                tot += __shfl_xor(tot, 16);
                tot += __shfl_xor(tot, 32);
                if (quad == 0) kred[wave][col] = tot;
                #pragma unroll
                for (int r = 0; r < 4; ++r)
                    tscr[(wave * 16 + quad * 4 + r) * 66 + col] =
                        __float2bfloat16(c[r] + bl);
            }
        }
        if (m > 0) {
            __syncthreads();
            if (tid < 64)
                ((m == 1) ? kpart : vpart)[(size_t)blockIdx.x * 64 + tid] =
                    kred[0][tid] + kred[1][tid] + 32.f * bias[tid];
            __hip_bfloat16* dst = (m == 1) ? ktb : vtb;
            #pragma unroll
            for (int i = 0; i < 2; ++i) {
                const int tsk = i * 128 + tid;     // 256 tasks: 64 h x 4 t-chunks
                const int hh = tsk >> 2, c8 = tsk & 3;
                short8 vv;
                #pragma unroll
                for (int j = 0; j < 8; ++j)
                    vv[j] = *(const short*)&tscr[(c8 * 8 + j) * 66 + hh];
                *(short8*)(dst + ((size_t)(b * HD + hh)) * SEQ + t0 + c8 * 8) = vv;
            }
            __syncthreads();
        }
    }
}

// ---------------------------------------------------------------------------
// Kernel 2: Gpart[h1][h2] += sum_t k[t][h1]*locv5[t][h2] per 32-t chunk (MFMA),
// grid (128, 5): y<4 = batch, y==4/x<16 = correction slab (ktot, Vtot, mktot,
// Mcorr, MT zero rows).  locv5_u = sum_{|e|<=2, in-range} v[u+e]  (exact swap
// of the banded summation; all invD edge terms live in Mcorr).
// ---------------------------------------------------------------------------
__global__ __launch_bounds__(256) void mkernel(
    const __hip_bfloat16* __restrict__ ktb, const __hip_bfloat16* __restrict__ vtb,
    const float* __restrict__ kpart, const float* __restrict__ vpart,
    __hip_bfloat16* __restrict__ Mpart, float* __restrict__ Mcorr,
    __hip_bfloat16* __restrict__ MT, float* __restrict__ Vtot)
{
    __shared__ float vws[64 * 38];              // v window [h][t0-2..t0+34)
    __shared__ __hip_bfloat16 lvt[64 * 40];     // locv5^T [h][32 t]
    __shared__ float scr[4][64];
    __shared__ float ktl[64], vtl[64];
    __shared__ float lc[4][64], vv_e[4][64];

    const int tid = threadIdx.x;

    if (blockIdx.y == 4) {
        // ---------------- correction slab ----------------
        if (blockIdx.x >= 16) return;
        const int b = blockIdx.x >> 2, slab = blockIdx.x & 3;
        const int h = tid & 63, g = tid >> 6;

        if (slab == 0 || slab == 3) {
            float kp = 0.f;
            for (int j = 0; j < 32; ++j)
                kp += kpart[(size_t)(b * 128 + g * 32 + j) * 64 + h];
            scr[g][h] = kp;
            __syncthreads();
            if (tid < 64) ktl[tid] = scr[0][tid] + scr[1][tid] + scr[2][tid] + scr[3][tid];
        }
        if (slab == 0) {
            __syncthreads();
            if (tid < 64) {
                const int hh = tid;
                const float kt = ktl[hh];
                const __hip_bfloat16* kr = ktb + (size_t)(b * 64 + hh) * SEQ;
                const float e0 = b2f(kr[0]), e1 = b2f(kr[1]), e2 = b2f(kr[2]), e3 = b2f(kr[3]);
                const float f0 = b2f(kr[SEQ-4]), f1 = b2f(kr[SEQ-3]);
                const float f2 = b2f(kr[SEQ-2]), f3 = b2f(kr[SEQ-1]);
                const float Sint = 5.f*kt - 4.f*e0 - 3.f*e1 - 2.f*e2 - e3
                                 - f0 - 2.f*f1 - 3.f*f2 - 4.f*f3;
                const float SlocD = Sint * INVD5
                                  + (e0+e1+e2 + f1+f2+f3) * INVD3
                                  + (e0+e1+e2+e3 + f0+f1+f2+f3) * INVD4;
                const float mktot = kt * (4092.f*INVD5 + 2.f*INVD4 + 2.f*INVD3) + EM1 * SlocD;
                MT[(size_t)b * 5120 + 64 * 64 + hh] = __float2bfloat16(mktot);
            }
        } else if (slab == 1) {
            float vp = 0.f;
            for (int j = 0; j < 32; ++j)
                vp += vpart[(size_t)(b * 128 + g * 32 + j) * 64 + h];
            scr[g][h] = vp;
            __syncthreads();
            if (tid < 64)
                Vtot[b * 64 + tid] = scr[0][tid] + scr[1][tid] + scr[2][tid] + scr[3][tid];
        } else if (slab == 2) {
            for (int i = tid; i < 15 * 64; i += 256)
                MT[(size_t)b * 5120 + 65 * 64 + i] = __float2bfloat16(0.f);
        } else {
            // slab 3: Mcorr = EM1*sum_edge dd_t*loc_t(x)v_t + ktot(x)VD
            __syncthreads();      // ktl ready
            {
                float vp = 0.f;
                for (int j = 0; j < 32; ++j)
                    vp += vpart[(size_t)(b * 128 + g * 32 + j) * 64 + h];
                scr[g][h] = vp;
            }
            __syncthreads();
            if (tid < 64) vtl[tid] = scr[0][tid] + scr[1][tid] + scr[2][tid] + scr[3][tid];
            if (tid < 64) {
                const int hh = tid;
                const __hip_bfloat16* kr = ktb + (size_t)(b * 64 + hh) * SEQ;
                const float e0 = b2f(kr[0]), e1 = b2f(kr[1]), e2 = b2f(kr[2]), e3 = b2f(kr[3]);
                const float f0 = b2f(kr[SEQ-4]), f1 = b2f(kr[SEQ-3]);
                const float f2 = b2f(kr[SEQ-2]), f3 = b2f(kr[SEQ-1]);
                lc[0][hh] = e0 + e1 + e2;
                lc[1][hh] = e0 + e1 + e2 + e3;
                lc[2][hh] = f0 + f1 + f2 + f3;
                lc[3][hh] = f1 + f2 + f3;
                const __hip_bfloat16* vr = vtb + (size_t)(b * 64 + hh) * SEQ;
                vv_e[0][hh] = b2f(vr[0]);
                vv_e[1][hh] = b2f(vr[1]);
                vv_e[2][hh] = b2f(vr[SEQ-2]);
                vv_e[3][hh] = b2f(vr[SEQ-1]);
            }
            __syncthreads();
            const float dd3 = INVD3 - INVD5, dd4 = INVD4 - INVD5;
            const int h1 = tid >> 2;
            const float l0 = lc[0][h1], l1 = lc[1][h1], l2 = lc[2][h1], l3 = lc[3][h1];
            const float kt1 = ktl[h1];
            #pragma unroll
            for (int j = 0; j < 16; ++j) {
                const int h2 = (tid & 3) * 16 + j;
                const float VD = INVD5 * vtl[h2]
                               + dd3 * (vv_e[0][h2] + vv_e[3][h2])
                               + dd4 * (vv_e[1][h2] + vv_e[2][h2]);
                const float mc = EM1 * (dd3 * (l0 * vv_e[0][h2] + l3 * vv_e[3][h2])
                                      + dd4 * (l1 * vv_e[1][h2] + l2 * vv_e[2][h2]))
                               + kt1 * VD;
                Mcorr[(size_t)(b * 64 + h1) * 64 + h2] = mc;
            }
        }
        return;
    }

    // ---------------- main GEMM chunk ----------------
    const int b = blockIdx.y, chunk = blockIdx.x;
    const int t0 = chunk * 32;

    // stage v window [t0-2, t0+34) as fp32, zero outside [0,S)
    for (int i = tid; i < 64 * 18; i += 256) {
        const int r = i / 18, c = i - r * 18;
        const int gt = t0 - 2 + c * 2;
        unsigned val = 0;
        if (gt >= 0 && gt <= SEQ - 2)
            val = *(const unsigned*)(vtb + (size_t)(b * 64 + r) * SEQ + gt);
        vws[r * 38 + c * 2]     = blo(val);
        vws[r * 38 + c * 2 + 1] = bhi(val);
    }
    __syncthreads();

    // locv5^T build: thread (h, g) -> 8 t's
    {
        const int h = tid & 63, g = tid >> 6;
        float w[12];
        #pragma unroll
        for (int j = 0; j < 12; ++j) w[j] = vws[h * 38 + g * 8 + j];
        short8 o;
        #pragma unroll
        for (int i = 0; i < 8; ++i)
            o[i] = bfs(w[i] + w[i+1] + w[i+2] + w[i+3] + w[i+4]);
        *(short8*)&lvt[h * 40 + g * 8] = o;
    }
    __syncthreads();

    // MFMA: A = k^T rows straight from global (h1-strip per wave), K=32
    const int wave = tid >> 6, lane = tid & 63, quad = lane >> 4, ln = lane & 15;
    short8 a = *(const short8*)(ktb + (size_t)(b * 64 + wave * 16 + ln) * SEQ
                                + t0 + quad * 8);
    f32x4 acc[4] = {};
    #pragma unroll
    for (int ct = 0; ct < 4; ++ct) {
        short8 bb = *(const short8*)&lvt[(ct * 16 + ln) * 40 + quad * 8];
        acc[ct] = mfma16(a, bb, acc[ct]);
    }
    __hip_bfloat16* mp = Mpart + (size_t)(b * 128 + chunk) * 4096;
    #pragma unroll
    for (int ct = 0; ct < 4; ++ct)
        #pragma unroll
        for (int r = 0; r < 4; ++r)
            mp[(wave * 16 + quad * 4 + r) * 64 + ct * 16 + ln] =
                __float2bfloat16(acc[ct][r]);
}

// ---------------------------------------------------------------------------
// Kernel 3: MT[h2][h1] = bf16(EM1*INVD5*sum_c Gpart + Mcorr[h1][h2]).
// grid (64, B): block per h1 row; 16 KB of reads per block.
// ---------------------------------------------------------------------------
__global__ __launch_bounds__(256) void mreduce_kernel(
    const __hip_bfloat16* __restrict__ Mpart, const float* __restrict__ Mcorr,
    __hip_bfloat16* __restrict__ MT)
{
    __shared__ float red[4][64];
    const int b = blockIdx.y, h1 = blockIdx.x;
    const int tid = threadIdx.x;
    const int g = tid >> 6, h2 = tid & 63;

    float s = 0.f;
    for (int c = g * 32; c < g * 32 + 32; ++c)
        s += b2f(Mpart[(size_t)(b * 128 + c) * 4096 + h1 * 64 + h2]);
    red[g][h2] = s;
    __syncthreads();
    if (tid < 64) {
        const float m = (EM1 * INVD5) * (red[0][tid] + red[1][tid] + red[2][tid] + red[3][tid])
                      + Mcorr[(size_t)(b * 64 + h1) * 64 + tid];
        MT[(size_t)b * 5120 + tid * 64 + h1] = __float2bfloat16(m);
    }
}

// ---------------------------------------------------------------------------
// Kernel 4: out = (Vtot + qs*M) / (4096 + qs*mktot) via MFMA.  grid 1024 x 64.
// ---------------------------------------------------------------------------
__global__ __launch_bounds__(64) void out_kernel(
    const __hip_bfloat16* __restrict__ qsb, const __hip_bfloat16* __restrict__ MT,
    const float* __restrict__ Vtot, float* __restrict__ out)
{
    const int tid = threadIdx.x;
    const int quad = tid >> 4, ln = tid & 15;
    const int R0 = blockIdx.x * 16;
    const int b = R0 >> 12;

    short8 qa0, qa1;
    {
        const __hip_bfloat16* qp = qsb + (size_t)(R0 + ln) * HD + quad * 8;
        qa0 = *(const short8*)qp;
        qa1 = *(const short8*)(qp + 32);
    }

    const __hip_bfloat16* mtb = MT + (size_t)b * 5120;
    f32x4 acc[5] = {};
    #pragma unroll
    for (int ct = 0; ct < 5; ++ct) {
        short8 b0 = *(const short8*)(mtb + (ct * 16 + ln) * 64 + quad * 8);
        short8 b1 = *(const short8*)(mtb + (ct * 16 + ln) * 64 + 32 + quad * 8);
        acc[ct] = mfma16(qa0, b0, acc[ct]);
        acc[ct] = mfma16(qa1, b1, acc[ct]);
    }

    float vt[4];
    #pragma unroll
    for (int ct = 0; ct < 4; ++ct) vt[ct] = Vtot[b * 64 + ct * 16 + ln];

    float inv[4];
    #pragma unroll
    for (int r = 0; r < 4; ++r) {
        const float den = __shfl(acc[4][r], tid & 48);   // col 0 of ct=4 tile
        inv[r] = 1.f / (4096.f + den);
    }
    #pragma unroll
    for (int ct = 0; ct < 4; ++ct)
        #pragma unroll
        for (int r = 0; r < 4; ++r)
            out[(size_t)(R0 + quad * 4 + r) * HD + ct * 16 + ln] =
                (vt[ct] + acc[ct][r]) * inv[r];
}

// ---------------------------------------------------------------------------
extern "C" void kernel_launch(void* const* d_in, const int* in_sizes, int n_in,
                              void* d_out, int out_size, void* d_ws, size_t ws_size,
                              hipStream_t stream)
{
    const float* feat = (const float*)d_in[0];
    const float* Wq = (const float*)d_in[1];
    const float* bq = (const float*)d_in[2];
    const float* Wk = (const float*)d_in[3];
    const float* bk = (const float*)d_in[4];
    const float* Wv = (const float*)d_in[5];
    const float* bv = (const float*)d_in[6];
    float* out = (float*)d_out;

    char* ws = (char*)d_ws;
    __hip_bfloat16* qsb   = (__hip_bfloat16*)(ws + 0);                     // 2 MB
    __hip_bfloat16* ktb   = (__hip_bfloat16*)(ws + (2u << 20));            // 2 MB
    __hip_bfloat16* vtb   = (__hip_bfloat16*)(ws + (4u << 20));            // 2 MB
    float*          kpart = (float*)(ws + (6u << 20));                     // 128 KB used
    float*          vpart = (float*)(ws + (6u << 20) + 262144);            // 128 KB used
    __hip_bfloat16* Mpart = (__hip_bfloat16*)(ws + (6u << 20) + 524288);   // 4 MB
    float*          Mcorr = (float*)(ws + (10u << 20) + 524288);           // 64 KB
    __hip_bfloat16* MT    = (__hip_bfloat16*)(ws + (10u << 20) + 589824);  // 40 KB
    float*          Vtot  = (float*)(ws + (10u << 20) + 630784);           // 1 KB

    proj_kernel<<<dim3(512), dim3(128), 0, stream>>>(
        feat, Wq, bq, Wk, bk, Wv, bv, qsb, ktb, vtb, kpart, vpart);
    mkernel<<<dim3(128, 5), dim3(256), 0, stream>>>(
        ktb, vtb, kpart, vpart, Mpart, Mcorr, MT, Vtot);
    mreduce_kernel<<<dim3(64, NBATCH), dim3(256), 0, stream>>>(Mpart, Mcorr, MT);
    out_kernel<<<dim3(1024), dim3(64), 0, stream>>>(qsb, MT, Vtot, out);
}